// Round 3
// baseline (1603.809 us; speedup 1.0000x reference)
//
#include <hip/hip_runtime.h>

#define HW 65536
#define IMG 256

__device__ __forceinline__ float hsum4(float4 v) { return v.x + v.y + v.z + v.w; }
__device__ __forceinline__ float lrelu(float v) { return v >= 0.f ? v : 0.2f * v; }

typedef const __attribute__((address_space(1))) unsigned int guint;
typedef __attribute__((address_space(3))) unsigned int luint;
__device__ __forceinline__ void gload_lds16(const float4* g, float4* l) {
    // direct global->LDS, 16B per lane; LDS dest = wave-uniform base + lane*16 (linear)
    __builtin_amdgcn_global_load_lds((guint*)(const void*)g, (luint*)(void*)l, 16, 0, 0);
}

// ---------------- 1x1 conv (v6): LDS-staged, double-buffered ----------------
// 512 threads = 8 waves. Wave wv owns COPW=CO/8 out-channels. Block owns 64 px-quads (q0).
// Input staged in 8-channel chunks via global_load_lds (1 KB per wave-instruction, one
// channel per wave per chunk), double-buffered; stage(next) issues BEFORE compute(cur) so
// HBM latency hides under the FMA phase; one __syncthreads per chunk.
// DUAL: CIT=128 split across two tensors (ci<64 from in, ci>=64 from in2).
// stats: gsel==-1 -> group = co0>=32 ; gsel==-2 -> group = co0>=64 ; else group 0.
// GNIN: per-input-channel GN affine + leaky-relu applied after the LDS read.
template<int CIT, int CO, bool GNIN, bool DUAL>
__global__ __launch_bounds__(512)
void conv1x1_v6(const float* __restrict__ in, int in_cs,
                const float* __restrict__ in2, int in2_cs,
                const float* __restrict__ w, int w_bstride,
                const float* __restrict__ bias,
                float* __restrict__ out, int out_cs, int out_coff,
                float* __restrict__ stats, int gsel,
                const float* __restrict__ gstats,
                const float* __restrict__ g_gamma, const float* __restrict__ g_beta,
                int g_coff, float g_Nf)
{
    constexpr int COPW = CO / 8;
    constexpr int NCHUNK = CIT / 8;
    __shared__ float4 Xs[2][8 * 64];      // 2 x 8 KiB
    const int b  = blockIdx.y;
    const int j  = threadIdx.x & 63;
    const int wv = __builtin_amdgcn_readfirstlane((int)(threadIdx.x >> 6));
    const int co0 = wv * COPW;
    const int q0 = blockIdx.x * 64;
    const float4* in4a = (const float4*)in + (size_t)b * in_cs * (HW/4) + q0 + j;
    const float4* in4b = DUAL ? ((const float4*)in2 + (size_t)b * in2_cs * (HW/4) + q0 + j)
                              : nullptr;
    const float* wb = w + (size_t)b * w_bstride;

    float gmean = 0.f, grstd = 0.f;
    if (GNIN) {
        gmean = gstats[b*4] / g_Nf;
        float var = gstats[b*4 + 1] / g_Nf - gmean * gmean;
        grstd = rsqrtf(var + 1e-5f);
    }

    float4 acc[COPW];
    #pragma unroll
    for (int k = 0; k < COPW; ++k) {
        float bv = bias ? bias[co0 + k] : 0.f;
        acc[k] = make_float4(bv, bv, bv, bv);
    }

    auto stage = [&](int ch, int bsel) {
        const int gci = ch * 8 + wv;      // one channel per wave per chunk
        const float4* src = (DUAL && gci >= 64)
            ? in4b + (size_t)(gci - 64) * (HW/4)
            : in4a + (size_t)gci * (HW/4);
        gload_lds16(src, &Xs[bsel][wv * 64]);
    };

    auto compute = [&](int ch, int bsel) {
        #pragma unroll
        for (int cl = 0; cl < 8; ++cl) {
            const int gci = ch * 8 + cl;
            float4 x = Xs[bsel][cl * 64 + j];
            if (GNIN) {
                float A = g_gamma[g_coff + gci] * grstd;
                float B = g_beta[g_coff + gci] - gmean * A;
                x.x = lrelu(fmaf(x.x, A, B));
                x.y = lrelu(fmaf(x.y, A, B));
                x.z = lrelu(fmaf(x.z, A, B));
                x.w = lrelu(fmaf(x.w, A, B));
            }
            const float* wr = wb + gci;
            #pragma unroll
            for (int k = 0; k < COPW; ++k) {
                float wk = wr[(size_t)(co0 + k) * CIT];
                acc[k].x = fmaf(wk, x.x, acc[k].x);
                acc[k].y = fmaf(wk, x.y, acc[k].y);
                acc[k].z = fmaf(wk, x.z, acc[k].z);
                acc[k].w = fmaf(wk, x.w, acc[k].w);
            }
        }
    };

    stage(0, 0);
    __syncthreads();                       // chunk 0 resident
    #pragma unroll
    for (int ch = 0; ch < NCHUNK; ++ch) {
        if (ch + 1 < NCHUNK) stage(ch + 1, (ch + 1) & 1);  // loads fly under compute
        compute(ch, ch & 1);
        __syncthreads();                   // drains stage(ch+1); WAR-protects buf reuse
    }

    if (!GNIN && stats) {
        float s = 0.f, ss = 0.f;
        #pragma unroll
        for (int k = 0; k < COPW; ++k) {
            s  += acc[k].x + acc[k].y + acc[k].z + acc[k].w;
            ss += acc[k].x*acc[k].x + acc[k].y*acc[k].y
                + acc[k].z*acc[k].z + acc[k].w*acc[k].w;
        }
        #pragma unroll
        for (int o = 32; o; o >>= 1) { s += __shfl_down(s, o, 64); ss += __shfl_down(ss, o, 64); }
        if (j == 0) {
            int g = 0;
            if (gsel == -1) g = (co0 >= 32) ? 1 : 0;
            else if (gsel == -2) g = (co0 >= 64) ? 1 : 0;
            float* st = stats + (size_t)b*4 + g*2;
            atomicAdd(st,     s);
            atomicAdd(st + 1, ss);
        }
    }

    float4* out4 = (float4*)out + ((size_t)b * out_cs + out_coff) * (HW/4) + q0 + j;
    #pragma unroll
    for (int k = 0; k < COPW; ++k)
        out4[(size_t)(co0 + k) * (HW/4)] = acc[k];
}

// ---------------- fused depthwise 5x5(pad2) -> 3x3(dil3,pad3), per channel ----------------
// grid: (4, 8, nb*64), block 256. 64 channels per dispatch via in_coff/w_coff.
__global__ __launch_bounds__(256)
void dwfused(const float* __restrict__ in, int in_cs, int in_coff,
             const float* __restrict__ w5, const float* __restrict__ b5, int w5_coff,
             const float* __restrict__ w3, const float* __restrict__ b3, int w3_coff,
             float* __restrict__ out, int out_cs, int out_coff)
{
    constexpr int TH = 32, TW = 64;
    constexpr int IN_H = TH + 10, IN_W = TW + 10;    // halo 5 = 3 (dil3 reach) + 2 (5x5 reach)
    constexpr int MID_H = TH + 6, MID_W = TW + 6;    // 5x5 output with 3-px halo
    constexpr int IN_RS = IN_W + 2;                  // 76
    constexpr int MID_RS = MID_W + 2;                // 72
    __shared__ float Xs[IN_H * IN_RS];               // 12.8 KiB
    __shared__ float Ms[MID_H * MID_RS];             // 10.9 KiB
    const int z = blockIdx.z;
    const int c = z & 63, b = z >> 6;
    const int x0 = blockIdx.x * TW, y0 = blockIdx.y * TH;
    const float* ip = in + ((size_t)b*in_cs + in_coff + c) * HW;

    float wk5[25];
    #pragma unroll
    for (int i = 0; i < 25; ++i) wk5[i] = w5[(size_t)(w5_coff + c)*25 + i];
    const float bv5 = b5[w5_coff + c];
    float wk3[9];
    #pragma unroll
    for (int i = 0; i < 9; ++i) wk3[i] = w3[(size_t)(w3_coff + c)*9 + i];
    const float bv3 = b3[w3_coff + c];

    for (int idx = threadIdx.x; idx < IN_H*IN_W; idx += 256) {
        int ly = idx / IN_W, lx = idx - ly*IN_W;
        int gy = y0 + ly - 5, gx = x0 + lx - 5;
        float v = 0.f;
        if (gy >= 0 && gy < IMG && gx >= 0 && gx < IMG)
            v = ip[gy*IMG + gx];
        Xs[ly*IN_RS + lx] = v;
    }
    __syncthreads();

    for (int idx = threadIdx.x; idx < MID_H*MID_W; idx += 256) {
        int my = idx / MID_W, mx = idx - my*MID_W;
        int gy = y0 + my - 3, gx = x0 + mx - 3;
        float v = 0.f;
        if (gy >= 0 && gy < IMG && gx >= 0 && gx < IMG) {
            v = bv5;
            #pragma unroll
            for (int ky = 0; ky < 5; ++ky) {
                const float* xr = &Xs[(my + ky)*IN_RS + mx];
                #pragma unroll
                for (int kx = 0; kx < 5; ++kx)
                    v = fmaf(wk5[ky*5 + kx], xr[kx], v);
            }
        }
        Ms[my*MID_RS + mx] = v;
    }
    __syncthreads();

    const int qx = (threadIdx.x & 15) * 4;
    const int ly0 = threadIdx.x >> 4;
    float* op = out + ((size_t)b*out_cs + out_coff + c) * HW;
    #pragma unroll
    for (int r = 0; r < 2; ++r) {
        const int oy = ly0 + r*16;
        float o0 = bv3, o1 = bv3, o2 = bv3, o3 = bv3;
        #pragma unroll
        for (int kt = 0; kt < 3; ++kt) {
            const float* mr = &Ms[(oy + 3*kt)*MID_RS + qx];
            #pragma unroll
            for (int kx = 0; kx < 3; ++kx) {
                float wv_ = wk3[kt*3 + kx];
                o0 = fmaf(wv_, mr[3*kx + 0], o0);
                o1 = fmaf(wv_, mr[3*kx + 1], o1);
                o2 = fmaf(wv_, mr[3*kx + 2], o2);
                o3 = fmaf(wv_, mr[3*kx + 3], o3);
            }
        }
        *(float4*)(op + (size_t)(y0 + oy)*IMG + x0 + qx) = make_float4(o0, o1, o2, o3);
    }
}

// ---------------- attention raw dots, with GN+leaky fused on q,k + post-act sumsq ----------------
// grid: (128, 4, nb), block 256. k tensor has stride k_cs (k lives in a 128-ch buffer).
__global__ __launch_bounds__(256)
void attn_dot_v4(const float* __restrict__ q, const float* __restrict__ k, int k_cs,
                 const float* __restrict__ stQ, const float* __restrict__ stK,
                 const float* __restrict__ qg, const float* __restrict__ qb,
                 const float* __restrict__ kg, const float* __restrict__ kb,
                 float* __restrict__ attn_raw,
                 float* __restrict__ ssq, float* __restrict__ ssk)
{
    __shared__ float4 qs[2048], ks[2048];   // 32 KiB each
    __shared__ float sred[512];
    const int h = blockIdx.y, b = blockIdx.z;
    const int t0 = blockIdx.x * 128;
    const int cc = threadIdx.x & 15;
    const int ch = h*16 + cc;

    const int gq = (ch >= 32) ? 1 : 0;
    float mq = stQ[b*4 + gq*2] / (32.f * HW);
    float vq = stQ[b*4 + gq*2 + 1] / (32.f * HW) - mq*mq;
    const float Aq = qg[ch] * rsqrtf(vq + 1e-5f);
    const float Bq = qb[ch] - mq * Aq;
    float mk = stK[b*4] / (64.f * HW);
    float vk = stK[b*4 + 1] / (64.f * HW) - mk*mk;
    const float Ak = kg[ch] * rsqrtf(vk + 1e-5f);
    const float Bk = kb[ch] - mk * Ak;

    const float4* q4 = (const float4*)q + ((size_t)b*64   + ch) * (HW/4) + t0;
    const float4* k4 = (const float4*)k + ((size_t)b*k_cs + ch) * (HW/4) + t0;
    float sq_acc = 0.f, sk_acc = 0.f;
    #pragma unroll
    for (int s = 0; s < 8; ++s) {
        int t = (threadIdx.x >> 4) + s*16;
        float4 v = q4[t];
        v.x = lrelu(fmaf(v.x, Aq, Bq)); v.y = lrelu(fmaf(v.y, Aq, Bq));
        v.z = lrelu(fmaf(v.z, Aq, Bq)); v.w = lrelu(fmaf(v.w, Aq, Bq));
        sq_acc += v.x*v.x + v.y*v.y + v.z*v.z + v.w*v.w;
        qs[t*16 + cc] = v;
        float4 u = k4[t];
        u.x = lrelu(fmaf(u.x, Ak, Bk)); u.y = lrelu(fmaf(u.y, Ak, Bk));
        u.z = lrelu(fmaf(u.z, Ak, Bk)); u.w = lrelu(fmaf(u.w, Ak, Bk));
        sk_acc += u.x*u.x + u.y*u.y + u.z*u.z + u.w*u.w;
        ks[t*16 + cc] = u;
    }
    sred[threadIdx.x]       = sq_acc;
    sred[256 + threadIdx.x] = sk_acc;
    __syncthreads();

    const int p   = threadIdx.x & 63;
    const int sub = threadIdx.x >> 6;
    const int c0 = (p >> 3) << 1, d0 = (p & 7) << 1;
    float4 a00 = make_float4(0,0,0,0), a01 = a00, a10 = a00, a11 = a00;
    #pragma unroll
    for (int i = 0; i < 32; ++i) {
        int t = sub*32 + i;
        float4 qa = qs[t*16 + c0], qb_ = qs[t*16 + c0 + 1];
        float4 ka = ks[t*16 + d0], kb_ = ks[t*16 + d0 + 1];
        a00.x = fmaf(qa.x, ka.x, a00.x); a00.y = fmaf(qa.y, ka.y, a00.y);
        a00.z = fmaf(qa.z, ka.z, a00.z); a00.w = fmaf(qa.w, ka.w, a00.w);
        a01.x = fmaf(qa.x, kb_.x, a01.x); a01.y = fmaf(qa.y, kb_.y, a01.y);
        a01.z = fmaf(qa.z, kb_.z, a01.z); a01.w = fmaf(qa.w, kb_.w, a01.w);
        a10.x = fmaf(qb_.x, ka.x, a10.x); a10.y = fmaf(qb_.y, ka.y, a10.y);
        a10.z = fmaf(qb_.z, ka.z, a10.z); a10.w = fmaf(qb_.w, ka.w, a10.w);
        a11.x = fmaf(qb_.x, kb_.x, a11.x); a11.y = fmaf(qb_.y, kb_.y, a11.y);
        a11.z = fmaf(qb_.z, kb_.z, a11.z); a11.w = fmaf(qb_.w, kb_.w, a11.w);
    }
    float* ar = attn_raw + ((size_t)b*4 + h) * 256;
    atomicAdd(&ar[(c0  )*16 + d0  ], hsum4(a00));
    atomicAdd(&ar[(c0  )*16 + d0+1], hsum4(a01));
    atomicAdd(&ar[(c0+1)*16 + d0  ], hsum4(a10));
    atomicAdd(&ar[(c0+1)*16 + d0+1], hsum4(a11));

    if (threadIdx.x < 16) {
        float s = 0.f;
        #pragma unroll
        for (int jj = 0; jj < 16; ++jj) s += sred[threadIdx.x + 16*jj];
        atomicAdd(&ssq[b*64 + h*16 + threadIdx.x], s);
    } else if (threadIdx.x < 32) {
        const int c2 = threadIdx.x - 16;
        float s = 0.f;
        #pragma unroll
        for (int jj = 0; jj < 16; ++jj) s += sred[256 + c2 + 16*jj];
        atomicAdd(&ssk[b*64 + h*16 + c2], s);
    }
}

// ---------------- softmax with l2-norm scaling + temperature ----------------
__global__ __launch_bounds__(256)
void attn_softmax_v2(const float* __restrict__ attn_raw,
                     const float* __restrict__ ssq, const float* __restrict__ ssk,
                     const float* __restrict__ temp, float* __restrict__ attn)
{
    const int h = blockIdx.x, b = blockIdx.y;
    const int c = threadIdx.x >> 4, d = threadIdx.x & 15;
    const float nq = fmaxf(sqrtf(ssq[b*64 + h*16 + c]), 1e-12f);
    const float nk = fmaxf(sqrtf(ssk[b*64 + h*16 + d]), 1e-12f);
    float logit = attn_raw[((size_t)b*4 + h)*256 + c*16 + d] / (nq * nk) * temp[h];
    float m = logit;
    #pragma unroll
    for (int o = 8; o; o >>= 1) m = fmaxf(m, __shfl_xor(m, o, 16));
    float e = expf(logit - m);
    float s = e;
    #pragma unroll
    for (int o = 8; o; o >>= 1) s += __shfl_xor(s, o, 16);
    attn[((size_t)b*4 + h)*256 + c*16 + d] = e / s;
}

// ---------------- M[b] = proj . blockdiag(attn[b]) ----------------
__global__ __launch_bounds__(256)
void build_m_v2(const float* __restrict__ attn, const float* __restrict__ proj_w,
                float* __restrict__ M)
{
    const int b = blockIdx.x;
    for (int i = threadIdx.x; i < 4096; i += 256) {
        int co = i >> 6, ci = i & 63;
        int h = ci >> 4, d = ci & 15;
        float s = 0.f;
        #pragma unroll
        for (int cc = 0; cc < 16; ++cc)
            s += proj_w[co*64 + h*16 + cc] * attn[((size_t)b*4 + h)*256 + cc*16 + d];
        M[(size_t)b*4096 + i] = s;
    }
}

extern "C" void kernel_launch(void* const* d_in, const int* in_sizes, int n_in,
                              void* d_out, int out_size, void* d_ws, size_t ws_size,
                              hipStream_t stream)
{
    const float* x       = (const float*)d_in[0];
    const float* y       = (const float*)d_in[1];
    const float* kv_w    = (const float*)d_in[2];
    const float* q_w     = (const float*)d_in[3];
    const float* proj_w  = (const float*)d_in[4];
    const float* kv_c0_w = (const float*)d_in[5];
    const float* kv_c0_b = (const float*)d_in[6];
    const float* kv_cs_w = (const float*)d_in[7];
    const float* kv_cs_b = (const float*)d_in[8];
    const float* kv_c1_w = (const float*)d_in[9];
    const float* kv_c1_b = (const float*)d_in[10];
    const float* kv_gn_g = (const float*)d_in[11];
    const float* kv_gn_b = (const float*)d_in[12];
    const float* q_c0_w  = (const float*)d_in[13];
    const float* q_c0_b  = (const float*)d_in[14];
    const float* q_cs_w  = (const float*)d_in[15];
    const float* q_cs_b  = (const float*)d_in[16];
    const float* q_c1_w  = (const float*)d_in[17];
    const float* q_c1_b  = (const float*)d_in[18];
    const float* q_gn_g  = (const float*)d_in[19];
    const float* q_gn_b  = (const float*)d_in[20];
    const float* temp    = (const float*)d_in[21];

    float* ws       = (float*)d_ws;
    float* statsKV  = ws;            // 4/batch  -> 16
    float* statsQ   = ws + 16;
    float* sumsq_k  = ws + 32;       // 64/batch -> 256
    float* sumsq_q  = ws + 288;
    float* attn_raw = ws + 544;      // 1024/batch -> 4096
    float* attn     = ws + 4640;
    float* Mw       = ws + 8736;     // 4096/batch -> 16384 (end 25120)
    float* big      = (float*)((char*)d_ws + 131072);

    const size_t perb_bytes = (size_t)192 * HW * 4;
    int nb = 1;
    if      (ws_size >= 131072 + 4*perb_bytes) nb = 4;
    else if (ws_size >= 131072 + 2*perb_bytes) nb = 2;

    hipMemsetAsync(d_ws, 0, 102400, stream);
    dim3 blk(256);
    dim3 blk5(512);

    for (int b0 = 0; b0 < 4; b0 += nb) {
        const float* xb = x + (size_t)b0*64*HW;
        const float* yb = y + (size_t)b0*64*HW;
        float* H1 = big;                          // nb*128*HW : kvpre out, later k(0:64)|v_raw(64:128)
        float* H2 = big + (size_t)nb*128*HW;      // nb*64*HW  : dw-out k-half, later q mid
        float* O  = (float*)d_out + (size_t)b0*64*HW;   // nb*64*HW : dw-out v-half, later q
        float* stK = statsKV + b0*4;
        float* stQ = statsQ  + b0*4;
        float* ssk = sumsq_k + b0*64;
        float* ssq = sumsq_q + b0*64;
        float* arw = attn_raw + b0*1024;
        float* atn = attn     + b0*1024;
        float* Mb  = Mw       + b0*4096;

        dim3 gdwf(4, 8, nb*64);
        dim3 gc(256, nb);

        // ---- kv chain ----
        conv1x1_v6<64,128,false,false><<<gc, blk5, 0, stream>>>(
            yb, 64, nullptr, 0, kv_w, 0, nullptr, H1, 128, 0,
            nullptr, 0, nullptr, nullptr, nullptr, 0, 0.f);
        dwfused<<<gdwf, blk, 0, stream>>>(H1, 128, 0,  kv_c0_w, kv_c0_b, 0,  kv_cs_w, kv_cs_b, 0,  H2, 64, 0);
        dwfused<<<gdwf, blk, 0, stream>>>(H1, 128, 64, kv_c0_w, kv_c0_b, 64, kv_cs_w, kv_cs_b, 64, O,  64, 0);
        conv1x1_v6<128,128,false,true><<<gc, blk5, 0, stream>>>(
            H2, 64, O, 64, kv_c1_w, 0, kv_c1_b, H1, 128, 0,
            stK, -2, nullptr, nullptr, nullptr, 0, 0.f);

        // ---- q chain (uses O and H2; H1 holds k/v) ----
        conv1x1_v6<64,64,false,false><<<gc, blk5, 0, stream>>>(
            xb, 64, nullptr, 0, q_w, 0, nullptr, O, 64, 0,
            nullptr, 0, nullptr, nullptr, nullptr, 0, 0.f);
        dwfused<<<gdwf, blk, 0, stream>>>(O, 64, 0, q_c0_w, q_c0_b, 0, q_cs_w, q_cs_b, 0, H2, 64, 0);
        conv1x1_v6<64,64,false,false><<<gc, blk5, 0, stream>>>(
            H2, 64, nullptr, 0, q_c1_w, 0, q_c1_b, O, 64, 0,
            stQ, -1, nullptr, nullptr, nullptr, 0, 0.f);

        // ---- attention ----
        attn_dot_v4<<<dim3(128,4,nb), blk, 0, stream>>>(O, H1, 128, stQ, stK,
                                                        q_gn_g, q_gn_b, kv_gn_g, kv_gn_b,
                                                        arw, ssq, ssk);
        attn_softmax_v2<<<dim3(4,nb), blk, 0, stream>>>(arw, ssq, ssk, temp, atn);
        build_m_v2<<<dim3(nb), blk, 0, stream>>>(atn, proj_w, Mb);

        // ---- out = M[b] @ leaky(GN(v_raw)), v_raw = H1[64:128]; writes d_out ----
        conv1x1_v6<64,64,true,false><<<gc, blk5, 0, stream>>>(
            H1 + (size_t)64*HW, 128, nullptr, 0, Mw + b0*4096, 4096, nullptr,
            (float*)d_out + (size_t)b0*64*HW, 64, 0,
            nullptr, 0, stK+2, kv_gn_g, kv_gn_b, 64, 64.f*HW);
    }
}

// Round 4
// 1017.477 us; speedup vs baseline: 1.5763x; 1.5763x over previous
//
#include <hip/hip_runtime.h>

#define HW 65536
#define IMG 256
// Blocked intermediate layout: [tile t = y/2][channel][512 px] — 2 KB per (t,c) granule.
// tile count per batch = 128; per-(t,c) float4 count = 128.

__device__ __forceinline__ float hsum4(float4 v) { return v.x + v.y + v.z + v.w; }
__device__ __forceinline__ float lrelu(float v) { return v >= 0.f ? v : 0.2f * v; }

// ---------------- 1x1 conv (v7): blocked-layout, contiguous block windows ----------------
// Block = one 2-row tile (128 quads) x all CO channels. Threads = CO*8: thread = (q, coh),
// q = tid & 127, coh = tid >> 7 (wave-uniform), co0 = coh*16, 16 co per thread.
// Inner loop = proven v3 pattern (1 load + 16 FMA4 per ci, unroll 4).
// INB: input blocked [t][cs][512]; else NCHW. OUTB: output blocked; else NCHW (final out).
// DUAL: ci 0..63 from in, 64..127 from in2 (both blocked, cs given per tensor).
// stats: gsel==-1 -> group = co0>=32 ; gsel==-2 -> group = co0>=64 ; else group 0.
// GNIN: per-input-channel GN affine + leaky-relu applied to loaded values.
template<int CIT, int CO, bool GNIN, bool DUAL, bool INB, bool OUTB>
__global__ __launch_bounds__(CO*8)
void conv1x1_v7(const float* __restrict__ in, int in_cs, int in_coff,
                const float* __restrict__ in2, int in2_cs,
                const float* __restrict__ w, int w_bstride,
                const float* __restrict__ bias,
                float* __restrict__ out, int out_cs, int out_coff,
                float* __restrict__ stats, int gsel,
                const float* __restrict__ gstats,
                const float* __restrict__ g_gamma, const float* __restrict__ g_beta,
                int g_coff, float g_Nf)
{
    const int b  = blockIdx.y;
    const int T  = blockIdx.x;                 // 2-row tile index
    const int q  = threadIdx.x & 127;          // quad within tile
    const int coh = __builtin_amdgcn_readfirstlane((int)(threadIdx.x >> 7));
    const int co0 = coh * 16;
    const float* wb = w + (size_t)b * w_bstride;

    float gmean = 0.f, grstd = 0.f;
    if (GNIN) {
        gmean = gstats[b*4] / g_Nf;
        float var = gstats[b*4 + 1] / g_Nf - gmean * gmean;
        grstd = rsqrtf(var + 1e-5f);
    }

    float4 acc[16];
    #pragma unroll
    for (int k = 0; k < 16; ++k) {
        float bv = bias ? bias[co0 + k] : 0.f;
        acc[k] = make_float4(bv, bv, bv, bv);
    }

    // run over n input channels from tensor base `t4` (blocked or NCHW), weight row base wrb,
    // gci0 = global input-channel offset (for weights / GN params)
    auto run = [&](const float4* t4, int cs, int coff, const float* wrb, int gci0, int n) {
        const float4* base = INB
            ? t4 + ((size_t)T * cs + coff) * 128 + q
            : t4 + (size_t)coff * (HW/4) + (size_t)T * 128 + q;
        const size_t cstr = INB ? 128 : (HW/4);
        #pragma unroll 4
        for (int ci = 0; ci < n; ++ci) {
            float4 x = base[(size_t)ci * cstr];
            if (GNIN) {
                float A = g_gamma[g_coff + gci0 + ci] * grstd;
                float B = g_beta[g_coff + gci0 + ci] - gmean * A;
                x.x = lrelu(fmaf(x.x, A, B));
                x.y = lrelu(fmaf(x.y, A, B));
                x.z = lrelu(fmaf(x.z, A, B));
                x.w = lrelu(fmaf(x.w, A, B));
            }
            const float* wr = wrb + gci0 + ci;
            #pragma unroll
            for (int k = 0; k < 16; ++k) {
                float wk = wr[(size_t)(co0 + k) * CIT];
                acc[k].x = fmaf(wk, x.x, acc[k].x);
                acc[k].y = fmaf(wk, x.y, acc[k].y);
                acc[k].z = fmaf(wk, x.z, acc[k].z);
                acc[k].w = fmaf(wk, x.w, acc[k].w);
            }
        }
    };

    const float4* inA = (const float4*)in + (size_t)b * in_cs * (HW/4);
    if (DUAL) {
        const float4* inB = (const float4*)in2 + (size_t)b * in2_cs * (HW/4);
        run(inA, in_cs, in_coff, wb, 0, 64);
        run(inB, in2_cs, 0, wb, 64, 64);
    } else {
        run(inA, in_cs, in_coff, wb, 0, CIT);
    }

    if (!GNIN && stats) {
        float s = 0.f, ss = 0.f;
        #pragma unroll
        for (int k = 0; k < 16; ++k) {
            s  += acc[k].x + acc[k].y + acc[k].z + acc[k].w;
            ss += acc[k].x*acc[k].x + acc[k].y*acc[k].y
                + acc[k].z*acc[k].z + acc[k].w*acc[k].w;
        }
        #pragma unroll
        for (int o = 32; o; o >>= 1) { s += __shfl_down(s, o, 64); ss += __shfl_down(ss, o, 64); }
        if ((threadIdx.x & 63) == 0) {
            int g = 0;
            if (gsel == -1) g = (co0 >= 32) ? 1 : 0;
            else if (gsel == -2) g = (co0 >= 64) ? 1 : 0;
            float* st = stats + (size_t)b*4 + g*2;
            atomicAdd(st,     s);
            atomicAdd(st + 1, ss);
        }
    }

    float4* ob = (float4*)out + (size_t)b * out_cs * (HW/4);
    #pragma unroll
    for (int k = 0; k < 16; ++k) {
        if (OUTB)
            ob[((size_t)T * out_cs + out_coff + co0 + k) * 128 + q] = acc[k];
        else
            ob[(size_t)(out_coff + co0 + k) * (HW/4) + (size_t)T * 128 + q] = acc[k];
    }
}

// ---------------- fused depthwise 5x5(pad2) -> 3x3(dil3,pad3), blocked layout ----------------
// grid: (4, 8, nb*64), block 256. 64 channels per dispatch via in_coff/w_coff.
// in/out are blocked [t=y/2][cs][512]; rows y, y+1 contiguous (2 KB granules).
__global__ __launch_bounds__(256)
void dwfused(const float* __restrict__ in, int in_cs, int in_coff,
             const float* __restrict__ w5, const float* __restrict__ b5, int w5_coff,
             const float* __restrict__ w3, const float* __restrict__ b3, int w3_coff,
             float* __restrict__ out, int out_cs, int out_coff)
{
    constexpr int TH = 32, TW = 64;
    constexpr int IN_H = TH + 10, IN_W = TW + 10;    // halo 5 = 3 (dil3) + 2 (5x5)
    constexpr int MID_H = TH + 6, MID_W = TW + 6;
    constexpr int IN_RS = IN_W + 2;                  // 76
    constexpr int MID_RS = MID_W + 2;                // 72
    __shared__ float Xs[IN_H * IN_RS];
    __shared__ float Ms[MID_H * MID_RS];
    const int z = blockIdx.z;
    const int c = z & 63, b = z >> 6;
    const int x0 = blockIdx.x * TW, y0 = blockIdx.y * TH;
    const float* ib = in + (size_t)b * in_cs * HW;

    float wk5[25];
    #pragma unroll
    for (int i = 0; i < 25; ++i) wk5[i] = w5[(size_t)(w5_coff + c)*25 + i];
    const float bv5 = b5[w5_coff + c];
    float wk3[9];
    #pragma unroll
    for (int i = 0; i < 9; ++i) wk3[i] = w3[(size_t)(w3_coff + c)*9 + i];
    const float bv3 = b3[w3_coff + c];

    for (int idx = threadIdx.x; idx < IN_H*IN_W; idx += 256) {
        int ly = idx / IN_W, lx = idx - ly*IN_W;
        int gy = y0 + ly - 5, gx = x0 + lx - 5;
        float v = 0.f;
        if (gy >= 0 && gy < IMG && gx >= 0 && gx < IMG)
            v = ib[((size_t)(gy >> 1) * in_cs + in_coff + c) * 512 + (gy & 1) * 256 + gx];
        Xs[ly*IN_RS + lx] = v;
    }
    __syncthreads();

    for (int idx = threadIdx.x; idx < MID_H*MID_W; idx += 256) {
        int my = idx / MID_W, mx = idx - my*MID_W;
        int gy = y0 + my - 3, gx = x0 + mx - 3;
        float v = 0.f;
        if (gy >= 0 && gy < IMG && gx >= 0 && gx < IMG) {
            v = bv5;
            #pragma unroll
            for (int ky = 0; ky < 5; ++ky) {
                const float* xr = &Xs[(my + ky)*IN_RS + mx];
                #pragma unroll
                for (int kx = 0; kx < 5; ++kx)
                    v = fmaf(wk5[ky*5 + kx], xr[kx], v);
            }
        }
        Ms[my*MID_RS + mx] = v;
    }
    __syncthreads();

    const int qx = (threadIdx.x & 15) * 4;
    const int ly0 = threadIdx.x >> 4;
    float* ob = out + (size_t)b * out_cs * HW;
    #pragma unroll
    for (int r = 0; r < 2; ++r) {
        const int oy = ly0 + r*16;
        float o0 = bv3, o1 = bv3, o2 = bv3, o3 = bv3;
        #pragma unroll
        for (int kt = 0; kt < 3; ++kt) {
            const float* mr = &Ms[(oy + 3*kt)*MID_RS + qx];
            #pragma unroll
            for (int kx = 0; kx < 3; ++kx) {
                float wv_ = wk3[kt*3 + kx];
                o0 = fmaf(wv_, mr[3*kx + 0], o0);
                o1 = fmaf(wv_, mr[3*kx + 1], o1);
                o2 = fmaf(wv_, mr[3*kx + 2], o2);
                o3 = fmaf(wv_, mr[3*kx + 3], o3);
            }
        }
        const int y = y0 + oy;
        *(float4*)(ob + ((size_t)(y >> 1) * out_cs + out_coff + c) * 512 + (y & 1) * 256 + x0 + qx) =
            make_float4(o0, o1, o2, o3);
    }
}

// ---------------- attention raw dots (blocked q/k), GN+leaky fused + post-act sumsq ----------------
// grid: (128, 4, nb), block 256. Block's 128-quad slice == exactly one 2-row tile T=blockIdx.x.
__global__ __launch_bounds__(256)
void attn_dot_v5(const float* __restrict__ qt, int q_cs,
                 const float* __restrict__ kt, int k_cs,
                 const float* __restrict__ stQ, const float* __restrict__ stK,
                 const float* __restrict__ qg, const float* __restrict__ qb,
                 const float* __restrict__ kg, const float* __restrict__ kb,
                 float* __restrict__ attn_raw,
                 float* __restrict__ ssq, float* __restrict__ ssk)
{
    __shared__ float4 qs[2048], ks[2048];   // 32 KiB each
    __shared__ float sred[512];
    const int h = blockIdx.y, b = blockIdx.z;
    const int T = blockIdx.x;
    const int cc = threadIdx.x & 15;
    const int ch = h*16 + cc;

    const int gq = (ch >= 32) ? 1 : 0;
    float mq = stQ[b*4 + gq*2] / (32.f * HW);
    float vq = stQ[b*4 + gq*2 + 1] / (32.f * HW) - mq*mq;
    const float Aq = qg[ch] * rsqrtf(vq + 1e-5f);
    const float Bq = qb[ch] - mq * Aq;
    float mk = stK[b*4] / (64.f * HW);
    float vk = stK[b*4 + 1] / (64.f * HW) - mk*mk;
    const float Ak = kg[ch] * rsqrtf(vk + 1e-5f);
    const float Bk = kb[ch] - mk * Ak;

    const float4* q4 = (const float4*)qt + (size_t)b*q_cs*(HW/4) + ((size_t)T*q_cs + ch)*128;
    const float4* k4 = (const float4*)kt + (size_t)b*k_cs*(HW/4) + ((size_t)T*k_cs + ch)*128;
    float sq_acc = 0.f, sk_acc = 0.f;
    #pragma unroll
    for (int s = 0; s < 8; ++s) {
        int t = (threadIdx.x >> 4) + s*16;
        float4 v = q4[t];
        v.x = lrelu(fmaf(v.x, Aq, Bq)); v.y = lrelu(fmaf(v.y, Aq, Bq));
        v.z = lrelu(fmaf(v.z, Aq, Bq)); v.w = lrelu(fmaf(v.w, Aq, Bq));
        sq_acc += v.x*v.x + v.y*v.y + v.z*v.z + v.w*v.w;
        qs[t*16 + cc] = v;
        float4 u = k4[t];
        u.x = lrelu(fmaf(u.x, Ak, Bk)); u.y = lrelu(fmaf(u.y, Ak, Bk));
        u.z = lrelu(fmaf(u.z, Ak, Bk)); u.w = lrelu(fmaf(u.w, Ak, Bk));
        sk_acc += u.x*u.x + u.y*u.y + u.z*u.z + u.w*u.w;
        ks[t*16 + cc] = u;
    }
    sred[threadIdx.x]       = sq_acc;
    sred[256 + threadIdx.x] = sk_acc;
    __syncthreads();

    const int p   = threadIdx.x & 63;
    const int sub = threadIdx.x >> 6;
    const int c0 = (p >> 3) << 1, d0 = (p & 7) << 1;
    float4 a00 = make_float4(0,0,0,0), a01 = a00, a10 = a00, a11 = a00;
    #pragma unroll
    for (int i = 0; i < 32; ++i) {
        int t = sub*32 + i;
        float4 qa = qs[t*16 + c0], qb_ = qs[t*16 + c0 + 1];
        float4 ka = ks[t*16 + d0], kb_ = ks[t*16 + d0 + 1];
        a00.x = fmaf(qa.x, ka.x, a00.x); a00.y = fmaf(qa.y, ka.y, a00.y);
        a00.z = fmaf(qa.z, ka.z, a00.z); a00.w = fmaf(qa.w, ka.w, a00.w);
        a01.x = fmaf(qa.x, kb_.x, a01.x); a01.y = fmaf(qa.y, kb_.y, a01.y);
        a01.z = fmaf(qa.z, kb_.z, a01.z); a01.w = fmaf(qa.w, kb_.w, a01.w);
        a10.x = fmaf(qb_.x, ka.x, a10.x); a10.y = fmaf(qb_.y, ka.y, a10.y);
        a10.z = fmaf(qb_.z, ka.z, a10.z); a10.w = fmaf(qb_.w, ka.w, a10.w);
        a11.x = fmaf(qb_.x, kb_.x, a11.x); a11.y = fmaf(qb_.y, kb_.y, a11.y);
        a11.z = fmaf(qb_.z, kb_.z, a11.z); a11.w = fmaf(qb_.w, kb_.w, a11.w);
    }
    float* ar = attn_raw + ((size_t)b*4 + h) * 256;
    atomicAdd(&ar[(c0  )*16 + d0  ], hsum4(a00));
    atomicAdd(&ar[(c0  )*16 + d0+1], hsum4(a01));
    atomicAdd(&ar[(c0+1)*16 + d0  ], hsum4(a10));
    atomicAdd(&ar[(c0+1)*16 + d0+1], hsum4(a11));

    if (threadIdx.x < 16) {
        float s = 0.f;
        #pragma unroll
        for (int jj = 0; jj < 16; ++jj) s += sred[threadIdx.x + 16*jj];
        atomicAdd(&ssq[b*64 + h*16 + threadIdx.x], s);
    } else if (threadIdx.x < 32) {
        const int c2 = threadIdx.x - 16;
        float s = 0.f;
        #pragma unroll
        for (int jj = 0; jj < 16; ++jj) s += sred[256 + c2 + 16*jj];
        atomicAdd(&ssk[b*64 + h*16 + c2], s);
    }
}

// ---------------- softmax with l2-norm scaling + temperature ----------------
__global__ __launch_bounds__(256)
void attn_softmax_v2(const float* __restrict__ attn_raw,
                     const float* __restrict__ ssq, const float* __restrict__ ssk,
                     const float* __restrict__ temp, float* __restrict__ attn)
{
    const int h = blockIdx.x, b = blockIdx.y;
    const int c = threadIdx.x >> 4, d = threadIdx.x & 15;
    const float nq = fmaxf(sqrtf(ssq[b*64 + h*16 + c]), 1e-12f);
    const float nk = fmaxf(sqrtf(ssk[b*64 + h*16 + d]), 1e-12f);
    float logit = attn_raw[((size_t)b*4 + h)*256 + c*16 + d] / (nq * nk) * temp[h];
    float m = logit;
    #pragma unroll
    for (int o = 8; o; o >>= 1) m = fmaxf(m, __shfl_xor(m, o, 16));
    float e = expf(logit - m);
    float s = e;
    #pragma unroll
    for (int o = 8; o; o >>= 1) s += __shfl_xor(s, o, 16);
    attn[((size_t)b*4 + h)*256 + c*16 + d] = e / s;
}

// ---------------- M[b] = proj . blockdiag(attn[b]) ----------------
__global__ __launch_bounds__(256)
void build_m_v2(const float* __restrict__ attn, const float* __restrict__ proj_w,
                float* __restrict__ M)
{
    const int b = blockIdx.x;
    for (int i = threadIdx.x; i < 4096; i += 256) {
        int co = i >> 6, ci = i & 63;
        int h = ci >> 4, d = ci & 15;
        float s = 0.f;
        #pragma unroll
        for (int cc = 0; cc < 16; ++cc)
            s += proj_w[co*64 + h*16 + cc] * attn[((size_t)b*4 + h)*256 + cc*16 + d];
        M[(size_t)b*4096 + i] = s;
    }
}

extern "C" void kernel_launch(void* const* d_in, const int* in_sizes, int n_in,
                              void* d_out, int out_size, void* d_ws, size_t ws_size,
                              hipStream_t stream)
{
    const float* x       = (const float*)d_in[0];
    const float* y       = (const float*)d_in[1];
    const float* kv_w    = (const float*)d_in[2];
    const float* q_w     = (const float*)d_in[3];
    const float* proj_w  = (const float*)d_in[4];
    const float* kv_c0_w = (const float*)d_in[5];
    const float* kv_c0_b = (const float*)d_in[6];
    const float* kv_cs_w = (const float*)d_in[7];
    const float* kv_cs_b = (const float*)d_in[8];
    const float* kv_c1_w = (const float*)d_in[9];
    const float* kv_c1_b = (const float*)d_in[10];
    const float* kv_gn_g = (const float*)d_in[11];
    const float* kv_gn_b = (const float*)d_in[12];
    const float* q_c0_w  = (const float*)d_in[13];
    const float* q_c0_b  = (const float*)d_in[14];
    const float* q_cs_w  = (const float*)d_in[15];
    const float* q_cs_b  = (const float*)d_in[16];
    const float* q_c1_w  = (const float*)d_in[17];
    const float* q_c1_b  = (const float*)d_in[18];
    const float* q_gn_g  = (const float*)d_in[19];
    const float* q_gn_b  = (const float*)d_in[20];
    const float* temp    = (const float*)d_in[21];

    float* ws       = (float*)d_ws;
    float* statsKV  = ws;            // 4/batch  -> 16
    float* statsQ   = ws + 16;
    float* sumsq_k  = ws + 32;       // 64/batch -> 256
    float* sumsq_q  = ws + 288;
    float* attn_raw = ws + 544;      // 1024/batch -> 4096
    float* attn     = ws + 4640;
    float* Mw       = ws + 8736;     // 4096/batch -> 16384 (end 25120)
    float* big      = (float*)((char*)d_ws + 131072);

    const size_t perb_bytes = (size_t)192 * HW * 4;
    int nb = 1;
    if      (ws_size >= 131072 + 4*perb_bytes) nb = 4;
    else if (ws_size >= 131072 + 2*perb_bytes) nb = 2;

    hipMemsetAsync(d_ws, 0, 102400, stream);
    dim3 blk(256);

    for (int b0 = 0; b0 < 4; b0 += nb) {
        const float* xb = x + (size_t)b0*64*HW;
        const float* yb = y + (size_t)b0*64*HW;
        float* H1 = big;                          // nb*128*HW : kvpre out (blocked), later k|v_raw
        float* H2 = big + (size_t)nb*128*HW;      // nb*64*HW  : dw-out k-half, later q mid (blocked)
        float* O  = (float*)d_out + (size_t)b0*64*HW;   // nb*64*HW scratch: dw-out v-half, later q
        float* stK = statsKV + b0*4;
        float* stQ = statsQ  + b0*4;
        float* ssk = sumsq_k + b0*64;
        float* ssq = sumsq_q + b0*64;
        float* arw = attn_raw + b0*1024;
        float* atn = attn     + b0*1024;
        float* Mb  = Mw       + b0*4096;

        dim3 gdwf(4, 8, nb*64);
        dim3 gcv(128, nb);

        // ---- kv chain ----
        // y (NCHW) -> H1 blocked 128ch
        conv1x1_v7<64,128,false,false,false,true><<<gcv, dim3(1024), 0, stream>>>(
            yb, 64, 0, nullptr, 0, kv_w, 0, nullptr, H1, 128, 0,
            nullptr, 0, nullptr, nullptr, nullptr, 0, 0.f);
        // fused dw5x5+dw3x3d3 (blocked in/out)
        dwfused<<<gdwf, blk, 0, stream>>>(H1, 128, 0,  kv_c0_w, kv_c0_b, 0,  kv_cs_w, kv_cs_b, 0,  H2, 64, 0);
        dwfused<<<gdwf, blk, 0, stream>>>(H1, 128, 64, kv_c0_w, kv_c0_b, 64, kv_cs_w, kv_cs_b, 64, O,  64, 0);
        // merged 128->128 1x1 (dual blocked input) -> H1 blocked: k(0:64) | v_raw(64:128), + GN stats
        conv1x1_v7<128,128,false,true,true,true><<<gcv, dim3(1024), 0, stream>>>(
            H2, 64, 0, O, 64, kv_c1_w, 0, kv_c1_b, H1, 128, 0,
            stK, -2, nullptr, nullptr, nullptr, 0, 0.f);

        // ---- q chain ----
        conv1x1_v7<64,64,false,false,false,true><<<gcv, dim3(512), 0, stream>>>(
            xb, 64, 0, nullptr, 0, q_w, 0, nullptr, O, 64, 0,
            nullptr, 0, nullptr, nullptr, nullptr, 0, 0.f);
        dwfused<<<gdwf, blk, 0, stream>>>(O, 64, 0, q_c0_w, q_c0_b, 0, q_cs_w, q_cs_b, 0, H2, 64, 0);
        conv1x1_v7<64,64,false,false,true,true><<<gcv, dim3(512), 0, stream>>>(
            H2, 64, 0, nullptr, 0, q_c1_w, 0, q_c1_b, O, 64, 0,
            stQ, -1, nullptr, nullptr, nullptr, 0, 0.f);

        // ---- attention (blocked q=O cs64, k=H1 cs128) ----
        attn_dot_v5<<<dim3(128,4,nb), blk, 0, stream>>>(O, 64, H1, 128, stQ, stK,
                                                        q_gn_g, q_gn_b, kv_gn_g, kv_gn_b,
                                                        arw, ssq, ssk);
        attn_softmax_v2<<<dim3(4,nb), blk, 0, stream>>>(arw, ssq, ssk, temp, atn);
        build_m_v2<<<dim3(nb), blk, 0, stream>>>(atn, proj_w, Mb);

        // ---- out = M[b] @ leaky(GN(v_raw)); v_raw = H1 blocked coff 64; out NCHW d_out ----
        conv1x1_v7<64,64,true,false,true,false><<<gcv, dim3(512), 0, stream>>>(
            H1, 128, 64, nullptr, 0, Mw + b0*4096, 4096, nullptr,
            (float*)d_out + (size_t)b0*64*HW, 64, 0,
            nullptr, 0, stK+2, kv_gn_g, kv_gn_b, 64, 64.f*HW);
    }
}